// Round 24
// baseline (85.720 us; speedup 1.0000x reference)
//
#include <hip/hip_runtime.h>

// LocalCrossCorrelation3D: I,J (2,1,96,192,192) fp32 -> (loss[2], cc[2,81,192,192])
// Window (16,9,9): depth valid (96->81), h/w zero-padded +-4.
// RESTRUCTURE: K1 = PURE-STREAM depth sliding sum (no LDS, no barriers),
// writes 5-ch d-summed bf16 planes (12B/voxel). K2 = fused w-box (LDS 3+3,
// 2 barriers/row, loads prefetched & independent) + h sliding box (full
// unroll + static ring) + cc + spread-slot loss atomics. K3 = slot reduce.

constexpr int N = 2, D = 96, H = 192, W = 192;
constexpr int OD = 81;            // D - 16 + 1
constexpr int KD = 16;
constexpr int HWp = H * W;        // 36864
constexpr float INV_WIN = 1.0f / 1296.0f;
constexpr float EPS_NZ = 3.0590232050182579e-07f;  // e^-15
constexpr int CH = 24;            // h-chunk per block in K2 (192/24 = 8)
constexpr int ODPB = 14;          // od-range per K1 block (9 blocks/CU)

__device__ __forceinline__ unsigned bf16rne(float f) {  // f32 -> bf16 bits (RNE)
  unsigned u = __float_as_uint(f);
  return (u + 0x7fffu + ((u >> 16) & 1u)) >> 16;
}
__device__ __forceinline__ float bf16tof(unsigned h) {  // bf16 bits -> f32
  return __uint_as_float(h << 16);
}

// ---------------------------------------------------------------------------
// K1 (k_d): per (n,h) row, stream depth with running 5-ch sums. NO LDS, NO
// barriers — pure per-thread stream with 2-round-deep prefetch (A/B slots).
// Snapshot for od covers slices [od, od+15] (post-add, pre-subtract).
// ws layout: [n][odi][h][w] x 3 uints (bf16 pairs: (sI,sJ),(sII,sJJ),(sIJ,_)).
__global__ __launch_bounds__(192)
void k_d(const float* __restrict__ I, const float* __restrict__ J,
         unsigned* __restrict__ ws, int od0, int c, int odcStride) {
  const int h = blockIdx.x;
  const int n = blockIdx.z;
  const int os = od0 + blockIdx.y * ODPB;
  int oe = od0 + c; if (os + ODPB < oe) oe = os + ODPB;
  if (os >= oe) return;
  const int w = threadIdx.x;

  const size_t colBase = ((size_t)n * D * H + h) * (size_t)W + w;
  const float* Ip = I + colBase;
  const float* Jp = J + colBase;
  unsigned* wbase = ws + ((size_t)n * odcStride * HWp + (size_t)h * W + w) * 3;

  // warm-up: accumulate slices [os, os+KD-2] (15 slices)
  float sI = 0.f, sJ = 0.f, sII = 0.f, sJJ = 0.f, sIJ = 0.f;
  for (int d = os; d < os + KD - 1; ++d) {
    const float iv = Ip[(size_t)d * HWp];
    const float jv = Jp[(size_t)d * HWp];
    sI += iv; sJ += jv;
    sII += iv * iv; sJJ += jv * jv; sIJ += iv * jv;
  }

#define ISSUE1(e_, f_, g_, h_, O)                                            \
  { const int _o = (O);                                                      \
    if (_o < oe) {                                                           \
      e_ = Ip[(size_t)(_o + KD - 1) * HWp];                                  \
      f_ = Jp[(size_t)(_o + KD - 1) * HWp];                                  \
      g_ = Ip[(size_t)_o * HWp];                                             \
      h_ = Jp[(size_t)_o * HWp]; } }

#define STEP1(O, e_, f_, g_, h_)                                             \
  { const int _od = (O);                                                     \
    sI += e_; sJ += f_;                                                      \
    sII += e_ * e_; sJJ += f_ * f_; sIJ += e_ * f_;                          \
    unsigned* o = wbase + (size_t)(_od - od0) * HWp * 3;                     \
    *(uint3*)o = make_uint3(bf16rne(sI) | (bf16rne(sJ) << 16),               \
                            bf16rne(sII) | (bf16rne(sJJ) << 16),             \
                            bf16rne(sIJ));                                   \
    sI -= g_; sJ -= h_;                                                      \
    sII -= g_ * g_; sJJ -= h_ * h_; sIJ -= g_ * h_; }

  float eA=0,fA=0,gA=0,hA=0, eB=0,fB=0,gB=0,hB=0;
  ISSUE1(eA, fA, gA, hA, os)
  ISSUE1(eB, fB, gB, hB, os + 1)
  for (int od = os; od < oe; od += 2) {
    STEP1(od, eA, fA, gA, hA)
    ISSUE1(eA, fA, gA, hA, od + 2)
    if (od + 1 < oe) {
      STEP1(od + 1, eB, fB, gB, hB)
      ISSUE1(eB, fB, gB, hB, od + 3)
    }
  }
#undef ISSUE1
#undef STEP1
}

// ---------------------------------------------------------------------------
// K2 (k_whcc): per (od, h-chunk, n). Per row t (hin = h0-4+t):
//   load d-summed packed row (prefetched 1 ahead, INDEPENDENT loads) ->
//   LDS xw; B1; stage1 3-tap (own word in regs) -> a (f32); B2; stage2
//   3-tap -> w-summed 5 floats; repack bf16 -> ring push; h-sum update;
//   cc at t>=8 with exact ring subtract. 2 raw barriers/row; loads are off
//   the barrier critical path. Loss -> 32 spread slots per batch.
// Hazard proof (2 barriers/row, single-buffered): xw-reads(t) drained by
// lgkmcnt(0) before B2(t), xw-write(t+1) after B2(t)... (write precedes
// B1(t+1): ordered after B2(t) in program order). a-reads(t) drained by
// lgkmcnt(0) before B1(t+1), a-write(t+1) after B1(t+1).
__global__ __launch_bounds__(192)
void k_whcc(const unsigned* __restrict__ ws, float* __restrict__ cc,
            float* __restrict__ acc, int od0, int odcStride) {
  const int odi = blockIdx.x;
  const int od = od0 + odi;
  const int h0 = blockIdx.y * CH;
  const int n = blockIdx.z;
  const int w = threadIdx.x;
  const unsigned* base =
      ws + ((size_t)n * odcStride * HWp + (size_t)odi * HWp + w) * 3;
  float* ccp = cc + ((size_t)n * OD + od) * (size_t)HWp + w;

  __shared__ unsigned xw0[W + 8], xw1[W + 8], xw2[W + 8];
  __shared__ float4 a4[W + 8];
  __shared__ float  a1[W + 8];

  if (w < 4) { xw0[w] = 0u; xw1[w] = 0u; xw2[w] = 0u; }
  if (w >= W - 4) { xw0[w + 8] = 0u; xw1[w + 8] = 0u; xw2[w + 8] = 0u; }
  __syncthreads();

  int pe = -1;                        // stage-1 halo position
  if (w < 3) pe = w + 1;              // covers a[1..3]
  else if (w >= W - 3) pe = w + 7;    // covers a[196..198]
  const int p = 4 + w;

  float s0 = 0.f, s1 = 0.f, s2 = 0.f, s3 = 0.f, s4 = 0.f;
  float lsum = 0.f;
  uint3 hist[8];
  const uint3 z3 = make_uint3(0u, 0u, 0u);

  // prefetch t=0 row (hin = h0-4 >= -4; <H always at t=0)
  uint3 vN = z3;
  {
    const int hin = h0 - 4;
    if (hin >= 0) vN = *(const uint3*)(base + (size_t)hin * W * 3);
  }
#pragma unroll
  for (int t = 0; t < CH + 8; ++t) {
    const uint3 v = vN;
    if (t + 1 < CH + 8) {             // prefetch next row (independent)
      const int hn = h0 - 4 + t + 1;
      vN = (hn >= 0 && hn < H) ? *(const uint3*)(base + (size_t)hn * W * 3) : z3;
    }
    // stage 0: row into LDS (own copy stays in regs)
    xw0[p] = v.x; xw1[p] = v.y; xw2[p] = v.z;
    asm volatile("s_waitcnt lgkmcnt(0)" ::: "memory");
    __builtin_amdgcn_s_barrier();     // B1: xw visible
    // stage 1: 3-tap (unpack bf16 -> f32 sums); own word from regs
    const unsigned m0 = xw0[p - 1], m1 = xw1[p - 1], m2 = xw2[p - 1];
    const unsigned q0 = xw0[p + 1], q1 = xw1[p + 1], q2 = xw2[p + 1];
    const float A0 = bf16tof(m0 & 0xffffu) + bf16tof(v.x & 0xffffu) + bf16tof(q0 & 0xffffu);
    const float A1 = bf16tof(m0 >> 16)     + bf16tof(v.x >> 16)     + bf16tof(q0 >> 16);
    const float A2 = bf16tof(m1 & 0xffffu) + bf16tof(v.y & 0xffffu) + bf16tof(q1 & 0xffffu);
    const float A3 = bf16tof(m1 >> 16)     + bf16tof(v.y >> 16)     + bf16tof(q1 >> 16);
    const float A4 = bf16tof(m2 & 0xffffu) + bf16tof(v.z & 0xffffu) + bf16tof(q2 & 0xffffu);
    a4[p] = make_float4(A0, A1, A2, A3); a1[p] = A4;
    if (pe >= 0) {                    // halo a-position, fully from LDS
      const unsigned e0 = xw0[pe - 1], e1 = xw1[pe - 1], e2 = xw2[pe - 1];
      const unsigned c0 = xw0[pe],     c1 = xw1[pe],     c2 = xw2[pe];
      const unsigned g0 = xw0[pe + 1], g1 = xw1[pe + 1], g2 = xw2[pe + 1];
      a4[pe] = make_float4(
        bf16tof(e0 & 0xffffu) + bf16tof(c0 & 0xffffu) + bf16tof(g0 & 0xffffu),
        bf16tof(e0 >> 16)     + bf16tof(c0 >> 16)     + bf16tof(g0 >> 16),
        bf16tof(e1 & 0xffffu) + bf16tof(c1 & 0xffffu) + bf16tof(g1 & 0xffffu),
        bf16tof(e1 >> 16)     + bf16tof(c1 >> 16)     + bf16tof(g1 >> 16));
      a1[pe] = bf16tof(e2 & 0xffffu) + bf16tof(c2 & 0xffffu) + bf16tof(g2 & 0xffffu);
    }
    asm volatile("s_waitcnt lgkmcnt(0)" ::: "memory");
    __builtin_amdgcn_s_barrier();     // B2: a visible
    // stage 2: 3-tap of stage-1 (own a in regs)
    const float4 bm = a4[p - 3]; const float em = a1[p - 3];
    const float4 bp = a4[p + 3]; const float ep = a1[p + 3];
    const float r0 = bm.x + A0 + bp.x;
    const float r1 = bm.y + A1 + bp.y;
    const float r2 = bm.z + A2 + bp.z;
    const float r3 = bm.w + A3 + bp.w;
    const float r4 = em + A4 + ep;
    // repack bf16 (ring stores packed -> exact add/sub symmetry)
    const uint3 pk = make_uint3(bf16rne(r0) | (bf16rne(r1) << 16),
                                bf16rne(r2) | (bf16rne(r3) << 16),
                                bf16rne(r4));
    s0 += bf16tof(pk.x & 0xffffu); s1 += bf16tof(pk.x >> 16);
    s2 += bf16tof(pk.y & 0xffffu); s3 += bf16tof(pk.y >> 16);
    s4 += bf16tof(pk.z & 0xffffu);
    if (t >= 8) {
      const int h = h0 + t - 8;
      const float cross = s4 - s0 * s1 * INV_WIN;
      const float vI = s2 - s0 * s0 * INV_WIN;
      const float vJ = s3 - s1 * s1 * INV_WIN;
      const float prod = vI * vJ;
      const float cv = (prod > EPS_NZ) ? (cross * cross) / (prod + EPS_NZ)
                                       : 1.0f / (1.0f + EPS_NZ);
      ccp[(size_t)h * W] = cv;
      lsum += cv;
      const uint3 q = hist[t & 7];    // row that entered 8 steps ago
      s0 -= bf16tof(q.x & 0xffffu); s1 -= bf16tof(q.x >> 16);
      s2 -= bf16tof(q.y & 0xffffu); s3 -= bf16tof(q.y >> 16);
      s4 -= bf16tof(q.z & 0xffffu);
    }
    hist[t & 7] = pk;                 // static index (full unroll)
  }
  __shared__ float red[3];
#pragma unroll
  for (int off = 32; off > 0; off >>= 1) lsum += __shfl_xor(lsum, off, 64);
  if ((threadIdx.x & 63) == 0) red[threadIdx.x >> 6] = lsum;
  __syncthreads();
  if (threadIdx.x == 0)
    atomicAdd(acc + n * 32 + (odi & 31), red[0] + red[1] + red[2]);
}

// ---------------------------------------------------------------------------
// K3: reduce the 64 spread slots (32 per batch) -> loss.
__global__ void k_fin(const float* __restrict__ acc, float* __restrict__ out) {
  const int t = threadIdx.x;            // 64 threads
  float v = acc[t];                     // slots [n*32 + k]
#pragma unroll
  for (int off = 16; off > 0; off >>= 1) v += __shfl_xor(v, off, 32);
  if (t == 0)  out[0] = 1.0f - v * (1.0f / 2985984.0f);
  if (t == 32) out[1] = 1.0f - v * (1.0f / 2985984.0f);
}

// ---------------------------------------------------------------------------
extern "C" void kernel_launch(void* const* d_in, const int* in_sizes, int n_in,
                              void* d_out, int out_size, void* d_ws,
                              size_t ws_size, hipStream_t stream) {
  const float* I = (const float*)d_in[0];
  const float* J = (const float*)d_in[1];
  float* out = (float*)d_out;
  float* acc = (float*)d_ws;                       // 64 fp32 spread slots
  unsigned* planes = (unsigned*)((char*)d_ws + 256);

  hipMemsetAsync(d_ws, 0, 64 * sizeof(float), stream);

  // adaptive od-chunking: packed voxel = 12B, two n-slabs
  const size_t perOdPerN = (size_t)HWp * 12;       // 442368 B
  size_t avail = (ws_size > 256) ? (ws_size - 256) : 0;
  long long odcMax = (long long)(avail / (2 * perOdPerN));
  if (odcMax < 1) odcMax = 1;
  if (odcMax > OD) odcMax = OD;
  const int odc = (int)odcMax;                     // slab stride (od entries)

  float* ccOut = out + 2;
  for (int od0 = 0; od0 < OD; od0 += odc) {
    const int c = (odc < OD - od0) ? odc : (OD - od0);
    const int S = (c + ODPB - 1) / ODPB;
    hipLaunchKernelGGL(k_d, dim3(H, S, N), dim3(192), 0, stream,
                       I, J, planes, od0, c, odc);
    hipLaunchKernelGGL(k_whcc, dim3(c, H / CH, N), dim3(192), 0, stream,
                       planes, ccOut, acc, od0, odc);
  }
  hipLaunchKernelGGL(k_fin, dim3(1), dim3(64), 0, stream, acc, out);
}

// Round 25
// 64.039 us; speedup vs baseline: 1.3386x; 1.3386x over previous
//
#include <hip/hip_runtime.h>

// LocalCrossCorrelation3D: I,J (2,1,96,192,192) fp32 -> (loss[2], cc[2,81,192,192])
// Window (16,9,9): depth valid (96->81), h/w zero-padded +-4.
// FINAL (best-measured, round 19: 63.8us; reproduced 64.4us):
// K1 = depth sliding sum + two-stage 3+3 w-box in float4 LDS, two od-outputs
// per barrier round, raw barriers, 2-round-deep prefetch. ws = AoS uint3
// bf16 (12B/voxel).
// K2 = h sliding box, full unroll + static 8-deep ring, CH=24, spread-slot
// loss atomics. K3 = slot reduce.

constexpr int N = 2, D = 96, H = 192, W = 192;
constexpr int OD = 81;            // D - 16 + 1
constexpr int KD = 16;
constexpr int HWp = H * W;        // 36864
constexpr float INV_WIN = 1.0f / 1296.0f;
constexpr float EPS_NZ = 3.0590232050182579e-07f;  // e^-15
constexpr int CH = 24;            // h-chunk per block in K2 (192/24 = 8)
constexpr int ODPB = 14;          // od-range per K1 block (9 blocks/CU)

__device__ __forceinline__ unsigned bf16rne(float f) {  // f32 -> bf16 bits (RNE)
  unsigned u = __float_as_uint(f);
  return (u + 0x7fffu + ((u >> 16) & 1u)) >> 16;
}
__device__ __forceinline__ float bf16tof(unsigned h) {  // bf16 bits -> f32
  return __uint_as_float(h << 16);
}

// ---------------------------------------------------------------------------
// K1. Per (n,h) row, stream depth with running 5-ch sums; snapshots for od
// and od+1 go to LDS buffer sets 0/1; one {B1,stage1x2,B2,stage2x2} round
// serves both. TWO rounds of enter/leave slices prefetched (slots A/B).
// ws layout: [n][odi][h][w] x 3 uints (bf16 pairs: (s0,s1),(s2,s3),(s4,_)).
__global__ __launch_bounds__(192)
void k_dw(const float* __restrict__ I, const float* __restrict__ J,
          unsigned* __restrict__ ws, int od0, int c, int odcStride) {
  const int h = blockIdx.x;
  const int n = blockIdx.z;
  const int os = od0 + blockIdx.y * ODPB;
  int oe = od0 + c; if (os + ODPB < oe) oe = os + ODPB;
  if (os >= oe) return;
  const int w = threadIdx.x;

  __shared__ float4 x4[2][W + 8];
  __shared__ float  x1[2][W + 8];
  __shared__ float4 a4[2][W + 8];
  __shared__ float  a1[2][W + 8];

  if (w < 4) {
    x4[0][w] = make_float4(0.f,0.f,0.f,0.f); x1[0][w] = 0.f;
    x4[1][w] = make_float4(0.f,0.f,0.f,0.f); x1[1][w] = 0.f;
  }
  if (w >= W - 4) {
    x4[0][w + 8] = make_float4(0.f,0.f,0.f,0.f); x1[0][w + 8] = 0.f;
    x4[1][w + 8] = make_float4(0.f,0.f,0.f,0.f); x1[1][w + 8] = 0.f;
  }
  __syncthreads();   // one safe barrier before the pipelined loop

  const size_t colBase = ((size_t)n * D * H + h) * (size_t)W + w;
  const float* Ip = I + colBase;
  const float* Jp = J + colBase;
  unsigned* wbase = ws + ((size_t)n * odcStride * HWp + (size_t)h * W + w) * 3;

  // extra a3 position for halo coverage (pe in 1..3 and 196..198)
  int pe = -1;
  if (w < 3) pe = w + 1;
  else if (w >= W - 3) pe = w + 7;
  const int p = 4 + w;

  // warm-up: accumulate slices [os, os+KD-2] (15 slices)
  float sI = 0.f, sJ = 0.f, sII = 0.f, sJJ = 0.f, sIJ = 0.f;
  for (int d = os; d < os + KD - 1; ++d) {
    const float iv = Ip[(size_t)d * HWp];
    const float jv = Jp[(size_t)d * HWp];
    sI += iv; sJ += jv;
    sII += iv * iv; sJJ += jv * jv; sIJ += iv * jv;
  }

  // ISSUE loads for the round starting at od=O into the given slot vars.
#define ISSUE(eA,fA,gA,hA_,eB,fB,gB,hB_, O)                                  \
  { const int _o = (O);                                                      \
    if (_o < oe) {                                                           \
      eA = Ip[(size_t)(_o + KD - 1) * HWp];                                  \
      fA = Jp[(size_t)(_o + KD - 1) * HWp];                                  \
      gA = Ip[(size_t)_o * HWp];                                             \
      hA_ = Jp[(size_t)_o * HWp];                                            \
      if (_o + 1 < oe) {                                                     \
        eB = Ip[(size_t)(_o + KD) * HWp];                                    \
        fB = Jp[(size_t)(_o + KD) * HWp];                                    \
        gB = Ip[(size_t)(_o + 1) * HWp];                                     \
        hB_ = Jp[(size_t)(_o + 1) * HWp];                                    \
      } } }

  // COMPUTE the 2-od round at od=O, consuming the slot vars (by value).
#define COMPUTE(O, eA,fA,gA,hA_,eB,fB,gB,hB_)                                \
  { const int _od = (O);                                                     \
    const bool two = (_od + 1 < oe);                                         \
    sI += eA; sJ += fA;                                                      \
    sII += eA * eA; sJJ += fA * fA; sIJ += eA * fA;                          \
    x4[0][p] = make_float4(sI, sJ, sII, sJJ); x1[0][p] = sIJ;                \
    sI -= gA; sJ -= hA_;                                                     \
    sII -= gA * gA; sJJ -= hA_ * hA_; sIJ -= gA * hA_;                       \
    if (two) {                                                               \
      sI += eB; sJ += fB;                                                    \
      sII += eB * eB; sJJ += fB * fB; sIJ += eB * fB;                        \
      x4[1][p] = make_float4(sI, sJ, sII, sJJ); x1[1][p] = sIJ;              \
      sI -= gB; sJ -= hB_;                                                   \
      sII -= gB * gB; sJJ -= hB_ * hB_; sIJ -= gB * hB_;                     \
    }                                                                        \
    asm volatile("s_waitcnt lgkmcnt(0)" ::: "memory");                       \
    __builtin_amdgcn_s_barrier();       /* B1: x visible */                  \
    {                                                                        \
      float4 m0 = x4[0][p - 1], m1 = x4[0][p], m2 = x4[0][p + 1];            \
      a4[0][p] = make_float4(m0.x + m1.x + m2.x, m0.y + m1.y + m2.y,         \
                             m0.z + m1.z + m2.z, m0.w + m1.w + m2.w);        \
      a1[0][p] = x1[0][p - 1] + x1[0][p] + x1[0][p + 1];                     \
      if (pe >= 0) {                                                         \
        float4 e0 = x4[0][pe - 1], e1 = x4[0][pe], e2 = x4[0][pe + 1];       \
        a4[0][pe] = make_float4(e0.x + e1.x + e2.x, e0.y + e1.y + e2.y,      \
                                e0.z + e1.z + e2.z, e0.w + e1.w + e2.w);     \
        a1[0][pe] = x1[0][pe - 1] + x1[0][pe] + x1[0][pe + 1];               \
      }                                                                      \
    }                                                                        \
    if (two) {                                                               \
      float4 m0 = x4[1][p - 1], m1 = x4[1][p], m2 = x4[1][p + 1];            \
      a4[1][p] = make_float4(m0.x + m1.x + m2.x, m0.y + m1.y + m2.y,         \
                             m0.z + m1.z + m2.z, m0.w + m1.w + m2.w);        \
      a1[1][p] = x1[1][p - 1] + x1[1][p] + x1[1][p + 1];                     \
      if (pe >= 0) {                                                         \
        float4 e0 = x4[1][pe - 1], e1 = x4[1][pe], e2 = x4[1][pe + 1];       \
        a4[1][pe] = make_float4(e0.x + e1.x + e2.x, e0.y + e1.y + e2.y,      \
                                e0.z + e1.z + e2.z, e0.w + e1.w + e2.w);     \
        a1[1][pe] = x1[1][pe - 1] + x1[1][pe] + x1[1][pe + 1];               \
      }                                                                      \
    }                                                                        \
    asm volatile("s_waitcnt lgkmcnt(0)" ::: "memory");                       \
    __builtin_amdgcn_s_barrier();       /* B2: a visible */                  \
    {                                                                        \
      float4 b0 = a4[0][p - 3], b1 = a4[0][p], b2 = a4[0][p + 3];            \
      const float r0 = b0.x + b1.x + b2.x;                                   \
      const float r1 = b0.y + b1.y + b2.y;                                   \
      const float r2 = b0.z + b1.z + b2.z;                                   \
      const float r3 = b0.w + b1.w + b2.w;                                   \
      const float r4 = a1[0][p - 3] + a1[0][p] + a1[0][p + 3];               \
      unsigned* o = wbase + (size_t)(_od - od0) * HWp * 3;                   \
      *(uint3*)o = make_uint3(bf16rne(r0) | (bf16rne(r1) << 16),             \
                              bf16rne(r2) | (bf16rne(r3) << 16),             \
                              bf16rne(r4));                                  \
    }                                                                        \
    if (two) {                                                               \
      float4 b0 = a4[1][p - 3], b1 = a4[1][p], b2 = a4[1][p + 3];            \
      const float r0 = b0.x + b1.x + b2.x;                                   \
      const float r1 = b0.y + b1.y + b2.y;                                   \
      const float r2 = b0.z + b1.z + b2.z;                                   \
      const float r3 = b0.w + b1.w + b2.w;                                   \
      const float r4 = a1[1][p - 3] + a1[1][p] + a1[1][p + 3];               \
      unsigned* o = wbase + (size_t)(_od + 1 - od0) * HWp * 3;               \
      *(uint3*)o = make_uint3(bf16rne(r0) | (bf16rne(r1) << 16),             \
                              bf16rne(r2) | (bf16rne(r3) << 16),             \
                              bf16rne(r4));                                  \
    } }

  // 2-round-deep prefetch: slots A (even rounds) and B (odd rounds)
  float eA0=0,fA0=0,gA0=0,hA0=0, eA1=0,fA1=0,gA1=0,hA1=0;
  float eB0=0,fB0=0,gB0=0,hB0=0, eB1=0,fB1=0,gB1=0,hB1=0;
  ISSUE(eA0,fA0,gA0,hA0,eA1,fA1,gA1,hA1, os)
  ISSUE(eB0,fB0,gB0,hB0,eB1,fB1,gB1,hB1, os + 2)

  for (int od = os; od < oe; od += 4) {
    COMPUTE(od, eA0,fA0,gA0,hA0,eA1,fA1,gA1,hA1)
    ISSUE(eA0,fA0,gA0,hA0,eA1,fA1,gA1,hA1, od + 4)
    if (od + 2 < oe) {
      COMPUTE(od + 2, eB0,fB0,gB0,hB0,eB1,fB1,gB1,hB1)
      ISSUE(eB0,fB0,gB0,hB0,eB1,fB1,gB1,hB1, od + 6)
    }
  }
#undef ISSUE
#undef COMPUTE
}

// ---------------------------------------------------------------------------
// K2: 9-wide h box via fully-unrolled stream with an 8-deep static ring
// (no subtract re-loads) + one-ahead prefetch; cc formula + loss reduction.
// Loss partial -> one of 32 spread slots per batch (atomic line-spread).
// Block: 192 threads = w-row, grid (od, h-chunk of 24, n).
__global__ __launch_bounds__(192)
void k_hcc(const unsigned* __restrict__ ws, float* __restrict__ cc,
           float* __restrict__ acc, int od0, int odcStride) {
  const int odi = blockIdx.x;
  const int od = od0 + odi;
  const int h0 = blockIdx.y * CH;
  const int n = blockIdx.z;
  const int w = threadIdx.x;
  const unsigned* base =
      ws + ((size_t)n * odcStride * HWp + (size_t)odi * HWp + w) * 3;
  float* ccp = cc + ((size_t)n * OD + od) * (size_t)HWp + w;

  float s0 = 0.f, s1 = 0.f, s2 = 0.f, s3 = 0.f, s4 = 0.f;
  float lsum = 0.f;
  uint3 hist[8];
  const uint3 z3 = make_uint3(0u, 0u, 0u);

  // prefetch t=0 row
  uint3 vN = z3;
  {
    const int hin = h0 - 4;
    if (hin >= 0) vN = *(const uint3*)(base + (size_t)hin * W * 3);
  }
#pragma unroll
  for (int t = 0; t < CH + 8; ++t) {
    const uint3 v = vN;
    // prefetch next row
    if (t + 1 < CH + 8) {
      const int hn = h0 - 4 + t + 1;
      vN = (hn >= 0 && hn < H) ? *(const uint3*)(base + (size_t)hn * W * 3) : z3;
    }
    s0 += bf16tof(v.x & 0xffffu); s1 += bf16tof(v.x >> 16);
    s2 += bf16tof(v.y & 0xffffu); s3 += bf16tof(v.y >> 16);
    s4 += bf16tof(v.z & 0xffffu);
    if (t >= 8) {
      const int h = h0 + t - 8;
      const float cross = s4 - s0 * s1 * INV_WIN;
      const float vI = s2 - s0 * s0 * INV_WIN;
      const float vJ = s3 - s1 * s1 * INV_WIN;
      const float prod = vI * vJ;
      const float c = (prod > EPS_NZ) ? (cross * cross) / (prod + EPS_NZ)
                                      : 1.0f / (1.0f + EPS_NZ);
      ccp[(size_t)h * W] = c;
      lsum += c;
      const uint3 q = hist[t & 7];       // row that entered 8 steps ago
      s0 -= bf16tof(q.x & 0xffffu); s1 -= bf16tof(q.x >> 16);
      s2 -= bf16tof(q.y & 0xffffu); s3 -= bf16tof(q.y >> 16);
      s4 -= bf16tof(q.z & 0xffffu);
    }
    hist[t & 7] = v;                     // static index (full unroll)
  }
  __shared__ float red[3];
#pragma unroll
  for (int off = 32; off > 0; off >>= 1) lsum += __shfl_xor(lsum, off, 64);
  if ((threadIdx.x & 63) == 0) red[threadIdx.x >> 6] = lsum;
  __syncthreads();
  if (threadIdx.x == 0)
    atomicAdd(acc + n * 32 + (odi & 31), red[0] + red[1] + red[2]);
}

// ---------------------------------------------------------------------------
// K3: reduce the 64 spread slots (32 per batch) -> loss.
__global__ void k_fin(const float* __restrict__ acc, float* __restrict__ out) {
  const int t = threadIdx.x;            // 64 threads
  float v = acc[t];                     // slots [n*32 + k]
#pragma unroll
  for (int off = 16; off > 0; off >>= 1) v += __shfl_xor(v, off, 32);
  if (t == 0)  out[0] = 1.0f - v * (1.0f / 2985984.0f);
  if (t == 32) out[1] = 1.0f - v * (1.0f / 2985984.0f);
}

// ---------------------------------------------------------------------------
extern "C" void kernel_launch(void* const* d_in, const int* in_sizes, int n_in,
                              void* d_out, int out_size, void* d_ws,
                              size_t ws_size, hipStream_t stream) {
  const float* I = (const float*)d_in[0];
  const float* J = (const float*)d_in[1];
  float* out = (float*)d_out;
  float* acc = (float*)d_ws;                       // 64 fp32 spread slots
  unsigned* planes = (unsigned*)((char*)d_ws + 256);

  hipMemsetAsync(d_ws, 0, 64 * sizeof(float), stream);

  // adaptive od-chunking: packed voxel = 12B, two n-slabs
  const size_t perOdPerN = (size_t)HWp * 12;       // 442368 B
  size_t avail = (ws_size > 256) ? (ws_size - 256) : 0;
  long long odcMax = (long long)(avail / (2 * perOdPerN));
  if (odcMax < 1) odcMax = 1;
  if (odcMax > OD) odcMax = OD;
  const int odc = (int)odcMax;                     // slab stride (od entries)

  float* ccOut = out + 2;
  for (int od0 = 0; od0 < OD; od0 += odc) {
    const int c = (odc < OD - od0) ? odc : (OD - od0);
    const int S = (c + ODPB - 1) / ODPB;
    hipLaunchKernelGGL(k_dw, dim3(H, S, N), dim3(192), 0, stream,
                       I, J, planes, od0, c, odc);
    hipLaunchKernelGGL(k_hcc, dim3(c, H / CH, N), dim3(192), 0, stream,
                       planes, ccOut, acc, od0, odc);
  }
  hipLaunchKernelGGL(k_fin, dim3(1), dim3(64), 0, stream, acc, out);
}